// Round 2
// baseline (824.175 us; speedup 1.0000x reference)
//
#include <hip/hip_runtime.h>
#include <hip/hip_bf16.h>

typedef __bf16 bf16x8 __attribute__((ext_vector_type(8)));
typedef float f32x4 __attribute__((ext_vector_type(4)));

constexpr int NUM_G = 16384;   // static segment count
constexpr int DIM = 128;       // D == HS == 128
constexpr int CHUNK = 128;     // rows per LDS chunk (covers ~all graphs in one pass)

// Kernel 0: seg[g] = first index v with batch[v] >= g (batch is sorted). seg[NUM_G] = V.
__global__ void seg_starts_kernel(const int* __restrict__ batch, int* __restrict__ seg, int V) {
    int v = blockIdx.x * blockDim.x + threadIdx.x;
    if (v >= V) return;
    int b1 = batch[v];
    int b0 = (v == 0) ? -1 : batch[v - 1];
    for (int g = b0 + 1; g <= b1; ++g) seg[g] = v;
    if (v == V - 1)
        for (int g = b1 + 1; g <= NUM_G; ++g) seg[g] = V;
}

// One block per graph (grid = NUM_G). Block turnover keeps some block staging at all
// times -> high HBM duty cycle (the R1 persistent design serialized stage/compute and
// sat at ~35% BW). W_proj fragments reloaded per block from L2 (64 KB, cached).
__launch_bounds__(256, 3)
__global__ void attn_agg_kernel(const float* __restrict__ Hm,
                                const float* __restrict__ Wp,
                                const float* __restrict__ bp,
                                const float* __restrict__ wsc,
                                const int* __restrict__ seg,
                                float* __restrict__ out) {
    __shared__ __align__(16) __bf16 Hs[CHUNK * DIM];  // 32 KB, XOR-swizzled
    __shared__ float e_part[2][CHUNK];                // per-nhalf partial e
    __shared__ float alpha_s[CHUNK];                  // exp(e) per row
    __shared__ float wsum[2][DIM];                    // weighted-sum halves
    __shared__ float red[4];                          // per-wave reduce scratch

    const int t = threadIdx.x;
    const int lane = t & 63;
    const int wave = t >> 6;
    const int l15 = lane & 15;
    const int lq = lane >> 4;      // 0..3
    const int mgrp = wave >> 1;    // m-tile parity (interleaved for load balance)
    const int nhalf = wave & 1;    // 0: n-tiles 0-3, 1: n-tiles 4-7

    // Preload W_proj B-fragments (bf16) + per-lane bias/score.
    // B[n][k]: lane holds n = lane&15 (+16*ntile), k = (lane>>4)*8 + j  (+32*kstep)
    bf16x8 bfrag[4][4];
    float bias_n[4], wsc_n[4];
#pragma unroll
    for (int nt = 0; nt < 4; ++nt) {
        int n_g = (nhalf * 4 + nt) * 16 + l15;
        bias_n[nt] = bp[n_g];
        wsc_n[nt] = wsc[n_g];
#pragma unroll
        for (int ks = 0; ks < 4; ++ks) {
            const float* src = Wp + n_g * DIM + ks * 32 + lq * 8;
            f32x4 w0 = *(const f32x4*)src;
            f32x4 w1 = *(const f32x4*)(src + 4);
            bf16x8 f;
            f[0] = (__bf16)w0[0]; f[1] = (__bf16)w0[1]; f[2] = (__bf16)w0[2]; f[3] = (__bf16)w0[3];
            f[4] = (__bf16)w1[0]; f[5] = (__bf16)w1[1]; f[6] = (__bf16)w1[2]; f[7] = (__bf16)w1[3];
            bfrag[nt][ks] = f;
        }
    }

    const int g = blockIdx.x;
    const int v0 = seg[g];
    const int n = seg[g + 1] - v0;

    const int col = t & 127;       // output column this thread owns
    const int hf = t >> 7;         // row parity for weighted sum (all 4 waves used)
    const int dch = col >> 3, doff = col & 7;
    float acc = 0.f;               // partial weighted sum for (hf, col)
    float lsum = 0.f;              // softmax denominator (|e| <~ 15, no max-shift needed)

    for (int r0 = 0; r0 < n; r0 += CHUNK) {
        int c = min(CHUNK, n - r0);
        __syncthreads();  // multi-chunk only (rare): previous readers done

        // Stage c rows of H -> LDS bf16, coalesced (thread t covers byte t*32 of the
        // contiguous [c x 128] fp32 block).
        for (int i = t; i < c * 16; i += 256) {
            int row = i >> 4, ch = i & 15;
            const float* src = Hm + (size_t)(v0 + r0 + row) * DIM + ch * 8;
            f32x4 a0 = *(const f32x4*)src;
            f32x4 a1 = *(const f32x4*)(src + 4);
            bf16x8 hv;
            hv[0] = (__bf16)a0[0]; hv[1] = (__bf16)a0[1]; hv[2] = (__bf16)a0[2]; hv[3] = (__bf16)a0[3];
            hv[4] = (__bf16)a1[0]; hv[5] = (__bf16)a1[1]; hv[6] = (__bf16)a1[2]; hv[7] = (__bf16)a1[3];
            int chs = ch ^ (row & 15);
            *(bf16x8*)&Hs[row * DIM + chs * 8] = hv;
        }
        __syncthreads();

        // Projection via MFMA over ceil(c/16) m-tiles, interleaved across wave pairs
        // (mtile = 2*mt + mgrp) so short graphs keep both wave pairs busy. Tiles
        // beyond c are skipped entirely (saves MFMA + tanh transcendentals).
#pragma unroll
        for (int mt = 0; mt < 4; ++mt) {
            int mtile = mt * 2 + mgrp;
            if (mtile * 16 < c) {
                int arow = mtile * 16 + l15;
                bf16x8 afrag[4];
#pragma unroll
                for (int ks = 0; ks < 4; ++ks) {
                    int chs = (ks * 4 + lq) ^ l15;
                    afrag[ks] = *(const bf16x8*)&Hs[arow * DIM + chs * 8];
                }
                float epl[4] = {0.f, 0.f, 0.f, 0.f};
#pragma unroll
                for (int nt = 0; nt < 4; ++nt) {
                    f32x4 dacc = {0.f, 0.f, 0.f, 0.f};
#pragma unroll
                    for (int ks = 0; ks < 4; ++ks)
                        dacc = __builtin_amdgcn_mfma_f32_16x16x32_bf16(afrag[ks], bfrag[nt][ks], dacc, 0, 0, 0);
                    // C/D layout: col = lane&15 (= n within tile), row = lq*4 + reg
#pragma unroll
                    for (int r = 0; r < 4; ++r) {
                        float x = dacc[r] + bias_n[nt];
                        float ex = __expf(2.f * x);                              // v_exp_f32
                        float th = 1.f - 2.f * __builtin_amdgcn_rcpf(ex + 1.f);  // tanh, NaN-free
                        epl[r] += th * wsc_n[nt];
                    }
                }
                // Reduce over the 16 columns this wave holds (lanes differing in bits 0-3)
#pragma unroll
                for (int m = 1; m < 16; m <<= 1)
#pragma unroll
                    for (int r = 0; r < 4; ++r)
                        epl[r] += __shfl_xor(epl[r], m, 64);
                if (l15 == 0)
#pragma unroll
                    for (int r = 0; r < 4; ++r)
                        e_part[nhalf][mtile * 16 + lq * 4 + r] = epl[r];
            }
        }
        __syncthreads();

        // Combine halves, exp, chunk denominator
        float pv = 0.f;
        if (t < c) {
            float ev = e_part[0][t] + e_part[1][t];
            float p = __expf(ev);
            alpha_s[t] = p;
            pv = p;
        }
#pragma unroll
        for (int m = 1; m < 64; m <<= 1) pv += __shfl_xor(pv, m, 64);
        if (lane == 0) red[wave] = pv;
        __syncthreads();
        lsum += red[0] + red[1] + red[2] + red[3];

        // Weighted sum on ALL 4 waves: thread (hf, col) sums rows r ≡ hf (mod 2).
        // alpha_s reads broadcast; Hs bf16 reads land 2 lanes/bank (free level).
        {
            int r = hf;
            for (; r + 6 < c; r += 8) {
                float p0 = alpha_s[r],     p1 = alpha_s[r + 2];
                float p2 = alpha_s[r + 4], p3 = alpha_s[r + 6];
                float h0 = (float)Hs[(r)     * DIM + ((dch ^ ((r)     & 15)) * 8) + doff];
                float h1 = (float)Hs[(r + 2) * DIM + ((dch ^ ((r + 2) & 15)) * 8) + doff];
                float h2 = (float)Hs[(r + 4) * DIM + ((dch ^ ((r + 4) & 15)) * 8) + doff];
                float h3 = (float)Hs[(r + 6) * DIM + ((dch ^ ((r + 6) & 15)) * 8) + doff];
                acc += p0 * h0 + p1 * h1 + p2 * h2 + p3 * h3;
            }
            for (; r < c; r += 2)
                acc += alpha_s[r] * (float)Hs[r * DIM + ((dch ^ (r & 15)) * 8) + doff];
        }
    }

    wsum[hf][col] = acc;
    __syncthreads();
    if (t < 128)
        out[(size_t)g * DIM + t] = (wsum[0][t] + wsum[1][t]) / fmaxf(lsum, 1e-12f);
    // n == 0: chunk loop skipped, acc = lsum = 0 -> out = 0, matching segment_sum on
    // empty segments (every output element is written each launch).
}

extern "C" void kernel_launch(void* const* d_in, const int* in_sizes, int n_in,
                              void* d_out, int out_size, void* d_ws, size_t ws_size,
                              hipStream_t stream) {
    const float* Hm  = (const float*)d_in[0];
    const int* batch = (const int*)d_in[1];   // int32 per harness convention
    const float* Wp  = (const float*)d_in[2];
    const float* bp  = (const float*)d_in[3];
    const float* wsc = (const float*)d_in[4];
    float* out = (float*)d_out;
    int* seg = (int*)d_ws;                    // (NUM_G+1) ints = 64 KB scratch
    int V = in_sizes[1];

    seg_starts_kernel<<<(V + 255) / 256, 256, 0, stream>>>(batch, seg, V);
    attn_agg_kernel<<<NUM_G, 256, 0, stream>>>(Hm, Wp, bp, wsc, seg, out);
}

// Round 3
// 697.385 us; speedup vs baseline: 1.1818x; 1.1818x over previous
//
#include <hip/hip_runtime.h>
#include <hip/hip_bf16.h>

typedef __bf16 bf16x8 __attribute__((ext_vector_type(8)));
typedef __bf16 bf16x2 __attribute__((ext_vector_type(2)));
typedef float f32x4 __attribute__((ext_vector_type(4)));

constexpr int NUM_G = 16384;   // static segment count
constexpr int DIM = 128;       // D == HS == 128
constexpr int CHUNK = 64;      // rows per LDS chunk (16 KB -> 6 blocks/CU resident)
constexpr int GPB = 11;        // consecutive graphs per block
constexpr int GRID = (NUM_G + GPB - 1) / GPB;  // 1490 blocks ≈ 5.8/CU: all resident

// Kernel 0: seg[g] = first index v with batch[v] >= g (batch is sorted). seg[NUM_G] = V.
__global__ void seg_starts_kernel(const int* __restrict__ batch, int* __restrict__ seg, int V) {
    int v = blockIdx.x * blockDim.x + threadIdx.x;
    if (v >= V) return;
    int b1 = batch[v];
    int b0 = (v == 0) ? -1 : batch[v - 1];
    for (int g = b0 + 1; g <= b1; ++g) seg[g] = v;
    if (v == V - 1)
        for (int g = b1 + 1; g <= NUM_G; ++g) seg[g] = V;
}

// Persistent-ish: GRID blocks, each owns GPB consecutive graphs. All blocks resident
// (6/CU: VGPR<=85 via launch_bounds(256,6), LDS ~19.3KB). W_proj fragments loaded ONCE
// per block (R2's per-graph preload cost 2.1 GB of L2 traffic + a serialized chain at
// every block start). Wave w owns n-quarter [32w, 32w+32) and iterates ALL m-tiles ->
// short graphs stay load-balanced across waves.
__launch_bounds__(256, 6)
__global__ void attn_agg_kernel(const float* __restrict__ Hm,
                                const float* __restrict__ Wp,
                                const float* __restrict__ bp,
                                const float* __restrict__ wsc,
                                const int* __restrict__ seg,
                                float* __restrict__ out) {
    __shared__ __align__(16) __bf16 Hs[CHUNK * DIM];  // 16 KB, XOR-swizzled
    __shared__ float e_part[4][CHUNK];                // per-wave (n-quarter) partial e
    __shared__ float alpha_s[CHUNK];                  // exp(e) per row
    __shared__ float wsum[4][DIM];                    // per-row-parity weighted sums
    __shared__ float red[4];                          // per-wave reduce scratch

    const int t = threadIdx.x;
    const int lane = t & 63;
    const int wave = t >> 6;
    const int l15 = lane & 15;
    const int lq = lane >> 4;      // 0..3

    // Preload W_proj B-fragments (bf16) + per-lane bias/score, ONCE per block.
    // Wave w holds n-tiles {2w, 2w+1}: B[n][k], lane n = lane&15, k = lq*8 + j (+32*ks)
    bf16x8 bfrag[2][4];
    float bias_n[2], wsc_n[2];
#pragma unroll
    for (int nt = 0; nt < 2; ++nt) {
        int n_g = (wave * 2 + nt) * 16 + l15;
        bias_n[nt] = bp[n_g];
        wsc_n[nt] = wsc[n_g];
#pragma unroll
        for (int ks = 0; ks < 4; ++ks) {
            const float* src = Wp + n_g * DIM + ks * 32 + lq * 8;
            f32x4 w0 = *(const f32x4*)src;
            f32x4 w1 = *(const f32x4*)(src + 4);
            bf16x8 f;
            f[0] = (__bf16)w0[0]; f[1] = (__bf16)w0[1]; f[2] = (__bf16)w0[2]; f[3] = (__bf16)w0[3];
            f[4] = (__bf16)w1[0]; f[5] = (__bf16)w1[1]; f[6] = (__bf16)w1[2]; f[7] = (__bf16)w1[3];
            bfrag[nt][ks] = f;
        }
    }

    const int g0 = blockIdx.x * GPB;
    const int g1 = min(g0 + GPB, NUM_G);
    if (g0 >= NUM_G) return;

    // Weighted-sum ownership: thread owns column pair (2*cp, 2*cp+1), row parity = wave.
    const int cp = lane;                       // 0..63
    const int dch = cp >> 2, dof = (cp & 3) * 4;  // byte offset within 16B chunk

    int s_prev = seg[g0];
    for (int g = g0; g < g1; ++g) {
        int s_next = seg[g + 1];
        int v0 = s_prev;
        int n = s_next - s_prev;
        s_prev = s_next;

        float acc0 = 0.f, acc1 = 0.f;  // weighted-sum partials for (wave, col pair)
        float lsum = 0.f;              // softmax denominator (|e| <~ 15: no max-shift)

        for (int r0 = 0; r0 < n; r0 += CHUNK) {
            int c = min(CHUNK, n - r0);
            __syncthreads();  // previous chunk/graph readers done before Hs overwrite

            // Stage c rows of H -> LDS bf16, coalesced (thread t covers byte t*32 of
            // the contiguous [c x 128] fp32 block), chunk index XOR-swizzled by row.
            for (int i = t; i < c * 16; i += 256) {
                int row = i >> 4, ch = i & 15;
                const float* src = Hm + (size_t)(v0 + r0 + row) * DIM + ch * 8;
                f32x4 a0 = *(const f32x4*)src;
                f32x4 a1 = *(const f32x4*)(src + 4);
                bf16x8 hv;
                hv[0] = (__bf16)a0[0]; hv[1] = (__bf16)a0[1]; hv[2] = (__bf16)a0[2]; hv[3] = (__bf16)a0[3];
                hv[4] = (__bf16)a1[0]; hv[5] = (__bf16)a1[1]; hv[6] = (__bf16)a1[2]; hv[7] = (__bf16)a1[3];
                int chs = ch ^ (row & 15);
                *(bf16x8*)&Hs[row * DIM + chs * 8] = hv;
            }
            __syncthreads();

            // Projection via MFMA: each wave does all live m-tiles for its 2 n-tiles.
#pragma unroll
            for (int mt = 0; mt < 4; ++mt) {
                if (mt * 16 < c) {
                    int arow = mt * 16 + l15;
                    bf16x8 afrag[4];
#pragma unroll
                    for (int ks = 0; ks < 4; ++ks) {
                        int chs = (ks * 4 + lq) ^ l15;
                        afrag[ks] = *(const bf16x8*)&Hs[arow * DIM + chs * 8];
                    }
                    float epl[4] = {0.f, 0.f, 0.f, 0.f};
#pragma unroll
                    for (int nt = 0; nt < 2; ++nt) {
                        f32x4 dacc = {0.f, 0.f, 0.f, 0.f};
#pragma unroll
                        for (int ks = 0; ks < 4; ++ks)
                            dacc = __builtin_amdgcn_mfma_f32_16x16x32_bf16(afrag[ks], bfrag[nt][ks], dacc, 0, 0, 0);
                        // C/D layout: col = lane&15 (n within tile), row = lq*4 + reg
#pragma unroll
                        for (int r = 0; r < 4; ++r) {
                            float x = dacc[r] + bias_n[nt];
                            float ex = __expf(2.f * x);                              // v_exp_f32
                            float th = 1.f - 2.f * __builtin_amdgcn_rcpf(ex + 1.f);  // tanh, NaN-free
                            epl[r] += th * wsc_n[nt];
                        }
                    }
                    // Reduce over this wave's 16 columns (lanes differing in bits 0-3)
#pragma unroll
                    for (int m = 1; m < 16; m <<= 1)
#pragma unroll
                        for (int r = 0; r < 4; ++r)
                            epl[r] += __shfl_xor(epl[r], m, 64);
                    if (l15 == 0)
#pragma unroll
                        for (int r = 0; r < 4; ++r)
                            e_part[wave][mt * 16 + lq * 4 + r] = epl[r];
                }
            }
            __syncthreads();

            // Combine quarters, exp, chunk denominator
            float pv = 0.f;
            if (t < c) {
                float ev = e_part[0][t] + e_part[1][t] + e_part[2][t] + e_part[3][t];
                float p = __expf(ev);
                alpha_s[t] = p;
                pv = p;
            }
#pragma unroll
            for (int m = 1; m < 64; m <<= 1) pv += __shfl_xor(pv, m, 64);
            if (lane == 0) red[wave] = pv;
            __syncthreads();
            lsum += red[0] + red[1] + red[2] + red[3];

            // Weighted sum: wave w sums rows r ≡ w (mod 4); lane owns 2 adjacent cols
            // via one ds_read_b32 (2-way bank level = free). alpha_s reads broadcast.
            {
                int r = wave;
                for (; r + 4 < c; r += 8) {
                    float p0 = alpha_s[r], p1 = alpha_s[r + 4];
                    bf16x2 h0 = *(const bf16x2*)((const char*)&Hs[(r)     * DIM + ((dch ^ ((r)     & 15)) * 8)] + dof);
                    bf16x2 h1 = *(const bf16x2*)((const char*)&Hs[(r + 4) * DIM + ((dch ^ ((r + 4) & 15)) * 8)] + dof);
                    acc0 += p0 * (float)h0[0] + p1 * (float)h1[0];
                    acc1 += p0 * (float)h0[1] + p1 * (float)h1[1];
                }
                for (; r < c; r += 4) {
                    float p = alpha_s[r];
                    bf16x2 h = *(const bf16x2*)((const char*)&Hs[r * DIM + ((dch ^ (r & 15)) * 8)] + dof);
                    acc0 += p * (float)h[0];
                    acc1 += p * (float)h[1];
                }
            }
        }

        // Combine row-parities and write out (also for n==0: zeros).
        *(float2*)&wsum[wave][cp * 2] = make_float2(acc0, acc1);
        __syncthreads();
        if (t < 128)
            out[(size_t)g * DIM + t] =
                (wsum[0][t] + wsum[1][t] + wsum[2][t] + wsum[3][t]) / fmaxf(lsum, 1e-12f);
        // wsum/Hs reuse by next graph is protected by the chunk-start barrier.
    }
}

extern "C" void kernel_launch(void* const* d_in, const int* in_sizes, int n_in,
                              void* d_out, int out_size, void* d_ws, size_t ws_size,
                              hipStream_t stream) {
    const float* Hm  = (const float*)d_in[0];
    const int* batch = (const int*)d_in[1];   // int32 per harness convention
    const float* Wp  = (const float*)d_in[2];
    const float* bp  = (const float*)d_in[3];
    const float* wsc = (const float*)d_in[4];
    float* out = (float*)d_out;
    int* seg = (int*)d_ws;                    // (NUM_G+1) ints = 64 KB scratch
    int V = in_sizes[1];

    seg_starts_kernel<<<(V + 255) / 256, 256, 0, stream>>>(batch, seg, V);
    attn_agg_kernel<<<GRID, 256, 0, stream>>>(Hm, Wp, bp, wsc, seg, out);
}